// Round 17
// baseline (173.099 us; speedup 1.0000x reference)
//
#include <hip/hip_runtime.h>

typedef _Float16 h16;
typedef h16 h8_t __attribute__((ext_vector_type(8)));
typedef h16 h4_t __attribute__((ext_vector_type(4)));
typedef float f4_t __attribute__((ext_vector_type(4)));
typedef unsigned int u32;
typedef u32 u4_t __attribute__((ext_vector_type(4)));

#define LOG2E 1.4426950408889634f
// (1/sqrt(32)) * log2(e)  -- folded into q columns of w_qkv^T
#define QSCALE 0.25505998f
#define SOFF 4.0f              // fixed softmax offset, folded into the bias table (log2 domain)

// workspace byte offsets
#define OFF_BIAS 0u
#define OFF_WQKV 524288u
#define OFF_WOUT 917504u
#define OFF_QKV  1048576u
// per-batch qkv block: Q 16MiB | K 16MiB | VT(B-frag order) 16MiB = 48MiB
#define WS_BBYTES 50331648u
#define WSTR_H    25165824u     // h16 elements per batch block
#define KOFF_H    8388608u      // K offset within block (h16 elems)
#define VOFF_H    16777216u     // VT offset within block
#define VT_WH     16384u        // h16 per (w,h) in VT

static __device__ __forceinline__ u32 pkrtz(float a, float b) {
    return __builtin_bit_cast(u32, __builtin_amdgcn_cvt_pkrtz(a, b));
}
static __device__ __forceinline__ h4_t pk4(float a, float b, float c, float d) {
    uint2 t; t.x = pkrtz(a, b); t.y = pkrtz(c, d);
    return __builtin_bit_cast(h4_t, t);
}

// ---------------- K0: precompute bias (fragment-ordered, log2 domain, -SOFF), w_qkv^T, w_out^T ----------------
// bias layout: [sq][kc][rf][cfp][hi*16+c][cf2][e]  (one b128 per (sq,kc,rf,cfp) per lane)
__global__ __launch_bounds__(256) void k0_prep(const float* __restrict__ wqkv,
                                               const float* __restrict__ pos,
                                               const float* __restrict__ wout,
                                               h16* __restrict__ bias,
                                               h16* __restrict__ wT,
                                               h16* __restrict__ wToT)
{
    const int bid = blockIdx.x;
    const int e = bid * 256 + threadIdx.x;
    if (bid < 1024) {
        int o = e;                      // 0..262143
        int e4  = o & 3;
        int cf2 = (o >> 2) & 1;
        int c   = (o >> 3) & 15;
        int hi  = (o >> 7) & 3;
        int cfp = (o >> 9) & 1;
        int rf  = (o >> 10) & 1;
        int kc  = (o >> 11) & 15;
        int sq  = o >> 15;
        int i = sq * 64 + (cfp * 2 + cf2) * 16 + c;   // query token
        int j = kc * 32 + rf * 16 + hi * 4 + e4;      // key token
        int ix = i >> 6, iy = (i >> 3) & 7, iz = i & 7;
        int jx = j >> 6, jy = (j >> 3) & 7, jz = j & 7;
        int r0 = jx - ix + 7, r1 = jy - iy + 7, r2 = jz - iz + 7;
        float v = pos[(r0 * 15 + r1) * 15 + r2] * LOG2E - SOFF;
        bias[o] = (h16)v;
    } else if (bid < 1792) {
        int t = e - 1024 * 256;
        int n = t >> 8, k = t & 255;
        float v = wqkv[k * 768 + n];
        if (n < 256) v *= QSCALE;          // scale the q channels
        wT[n * 256 + k] = (h16)v;
    } else {
        int t = e - 1792 * 256;
        int n = t >> 8, k = t & 255;
        wToT[n * 256 + k] = (h16)wout[k * 256 + n];
    }
}

// ---------------- K1: QKV projection, fused roll + window reorder ----------------
// V stored in exact MFMA-B-frag order: VT[(w,h)][kc][dh][lane=hi*16+c][rf*4+e]
// V epilogue goes through LDS (xs reuse) so global V stores are coalesced b128
// (R12 lesson: 64 scalar 2B stores per V-wave made k1 store-pipe-bound, 66->107us).
__global__ __launch_bounds__(768) __attribute__((amdgpu_waves_per_eu(3, 6)))
void k1_qkv(const float* __restrict__ x,
            const h16* __restrict__ wT,
            h16* __restrict__ qkv,
            unsigned long xstr, unsigned long wstr)
{
    __shared__ __align__(16) h16 xs[64 * 256];   // 32KB: fp16 x-tile, then V staging
    const int b = blockIdx.y;
    const float* xb = x + (unsigned long)b * xstr;
    h16* Qo = qkv + (unsigned long)b * wstr;
    h16* Ko = Qo + KOFF_H;
    h16* Vt = Qo + VOFF_H;

    const int tid = threadIdx.x;
    const int tile = blockIdx.x;                  // w*8 + st
    const int st = tile & 7, w = tile >> 3;
    const int wh = w >> 4, ww = (w >> 2) & 3, wd = w & 3;
    const int Xs = (wh * 8 + st + 4) & 31;        // roll(-4)

    for (int i = tid; i < 4096; i += 768) {       // 64 rows x 64 16B-segments (f32)
        int row = i >> 6, seg = i & 63;
        int iw = row >> 3, id = row & 7;
        int Y = (ww * 8 + iw + 4) & 31, Z = (wd * 8 + id + 4) & 31;
        const float* xp = xb + ((Xs * 32 + Y) * 32 + Z) * 256 + seg * 4;
        f4_t v = *(const f4_t*)xp;
        uint2 tmp;
        tmp.x = pkrtz(v[0], v[1]);
        tmp.y = pkrtz(v[2], v[3]);
        *(uint2*)((char*)xs + row * 512 + (((u32)(seg * 8)) ^ ((u32)(row & 7) << 4))) = tmp;
    }
    __syncthreads();

    const int wv = tid >> 6, lane = tid & 63;
    const int c = lane & 15, hi = lane >> 4;
    f4_t acc[4][4];
#pragma unroll
    for (int i = 0; i < 4; ++i)
#pragma unroll
        for (int j = 0; j < 4; ++j) { f4_t z = {0.f, 0.f, 0.f, 0.f}; acc[i][j] = z; }

#pragma unroll 2
    for (int ks = 0; ks < 8; ++ks) {
        h8_t a[4], bfr[4];
#pragma unroll
        for (int rf = 0; rf < 4; ++rf)
            a[rf] = *(const h8_t*)(wT + (wv * 64 + rf * 16 + c) * 256 + ks * 32 + hi * 8);
#pragma unroll
        for (int cf = 0; cf < 4; ++cf) {
            int tok = cf * 16 + c;
            bfr[cf] = *(const h8_t*)((const char*)xs + tok * 512 +
                                     (((u32)(ks * 64 + hi * 16)) ^ ((u32)(tok & 7) << 4)));
        }
#pragma unroll
        for (int rf = 0; rf < 4; ++rf)
#pragma unroll
            for (int cf = 0; cf < 4; ++cf)
                acc[rf][cf] = __builtin_amdgcn_mfma_f32_16x16x32_f16(a[rf], bfr[cf], acc[rf][cf], 0, 0, 0);
    }

    const int wbh = w * 8;
    // Q/K waves: direct global stores (8B, line-assembling across rf) -- no xs dependency
    if (wv < 8) {
#pragma unroll
        for (int rf = 0; rf < 4; ++rf) {
            const int ch = wv * 64 + rf * 16 + hi * 4;
            const int sel = ch >> 8;                  // 0=q 1=k (uniform per wave)
            const int ch2 = ch & 255, hh2 = ch2 >> 5, d0 = ch2 & 31;
#pragma unroll
            for (int cf = 0; cf < 4; ++cf) {
                const int t = st * 64 + cf * 16 + c;
                f4_t v = acc[rf][cf];
                h16* qp = (sel ? Ko : Qo) + ((wbh + hh2) * 512 + t) * 32 + d0;
                uint2 sv;
                sv.x = pkrtz(v[0], v[1]);
                sv.y = pkrtz(v[2], v[3]);
                *(uint2*)qp = sv;
            }
        }
    }
    __syncthreads();          // all xs READS (bfr) complete before V staging overwrites
    if (wv >= 8) {
        // V waves: scatter h16 into xs at B-frag offsets (identical algebra to the
        // R11/R12-proven direct store; st*64 multiples drop out of the low bits)
#pragma unroll
        for (int rf = 0; rf < 4; ++rf) {
            const int ch2 = (wv - 8) * 64 + rf * 16 + hi * 4;
            const int hh2 = ch2 >> 5, d0 = ch2 & 31;
            const int bh = hh2 * 2048 + (d0 >> 4) * 512 + (d0 & 15) * 8;
#pragma unroll
            for (int cf = 0; cf < 4; ++cf) {
                const int tl = cf * 16 + c;
                const int bt = (tl >> 5) * 1024 + ((tl >> 2) & 3) * 128 +
                               ((tl >> 4) & 1) * 4 + (tl & 3);
                f4_t v = acc[rf][cf];
#pragma unroll
                for (int r = 0; r < 4; ++r)
                    xs[bh + bt + r * 8] = (h16)v[r];
            }
        }
    }
    __syncthreads();          // V staging complete
    // cooperative coalesced copy: 2048 x 16B chunks; per head one contiguous 4KB run
    {
        h16* Vw = Vt + (unsigned long)wbh * VT_WH + st * 2048;
        for (int i = tid; i < 2048; i += 768) {
            const int hh2 = i >> 8, rem = i & 255;
            h8_t vchunk = *(const h8_t*)(xs + i * 8);
            *(h8_t*)(Vw + hh2 * VT_WH + rem * 8) = vchunk;
        }
    }
}

// One kv-chunk phase of the flash loop. All buffer references are NAMED arrays
// indexed only by compile-time constants -> can never be demoted to scratch
// (R11 lesson: runtime cur/nxt indexing put kf/bb/vv in L2-resident scratch,
// invisible in HBM counters, 39x slowdown).
// R17: V joins the named double-buffer (it was loaded in-phase ~50cyc before
// use vs ~200cyc L2 latency -- the last unprefetched stream).
#define KA_PHASE(KFC, BBC, VVC, KFN, BBN, VVN, KC, PREF) do {                           \
    if (PREF) {                                                                         \
        const int kt1_ = ((KC) + 1) * 32;                                               \
        KFN[0] = *(const h8_t*)(Kp + (kt1_ + c) * 32 + hi * 8);                         \
        KFN[1] = *(const h8_t*)(Kp + (kt1_ + 16 + c) * 32 + hi * 8);                    \
        VVN[0] = *(const h8_t*)(Vp + ((KC) + 1) * 1024 + lane * 8);                     \
        VVN[1] = *(const h8_t*)(Vp + ((KC) + 1) * 1024 + 512 + lane * 8);               \
        _Pragma("unroll")                                                               \
        for (int t = 0; t < 4; ++t)                                                     \
            BBN[t] = *(const h8_t*)(Bq + (((KC) + 1) * 4 + t) * 512);                   \
    }                                                                                   \
    const u4_t vw0 = __builtin_bit_cast(u4_t, VVC[0]);                                  \
    const u4_t vw1 = __builtin_bit_cast(u4_t, VVC[1]);                                  \
    _Pragma("unroll")                                                                   \
    for (int rf = 0; rf < 2; ++rf) {                                                    \
        uint2 vt0; vt0.x = vw0[rf * 2]; vt0.y = vw0[rf * 2 + 1];                        \
        uint2 vt1; vt1.x = vw1[rf * 2]; vt1.y = vw1[rf * 2 + 1];                        \
        const h4_t vB0 = __builtin_bit_cast(h4_t, vt0);                                 \
        const h4_t vB1 = __builtin_bit_cast(h4_t, vt1);                                 \
        _Pragma("unroll")                                                               \
        for (int cfp = 0; cfp < 2; ++cfp) {                                             \
            h8_t bv = BBC[rf * 2 + cfp];                                                \
            _Pragma("unroll")                                                           \
            for (int cf2 = 0; cf2 < 2; ++cf2) {                                         \
                const int cf = cfp * 2 + cf2;                                           \
                f4_t si;                                                                \
                si[0] = (float)bv[cf2 * 4 + 0];                                         \
                si[1] = (float)bv[cf2 * 4 + 1];                                         \
                si[2] = (float)bv[cf2 * 4 + 2];                                         \
                si[3] = (float)bv[cf2 * 4 + 3];                                         \
                f4_t s = __builtin_amdgcn_mfma_f32_16x16x32_f16(KFC[rf], qf[cf], si, 0, 0, 0); \
                float p0 = __builtin_amdgcn_exp2f(s[0]);                                \
                float p1 = __builtin_amdgcn_exp2f(s[1]);                                \
                float p2 = __builtin_amdgcn_exp2f(s[2]);                                \
                float p3 = __builtin_amdgcn_exp2f(s[3]);                                \
                l[cf] += (p0 + p1) + (p2 + p3);                                         \
                const h4_t pa = pk4(p0, p1, p2, p3);                                    \
                acc[cf][0] = __builtin_amdgcn_mfma_f32_16x16x16f16(pa, vB0, acc[cf][0], 0, 0, 0); \
                acc[cf][1] = __builtin_amdgcn_mfma_f32_16x16x16f16(pa, vB1, acc[cf][1], 0, 0, 0); \
            }                                                                           \
        }                                                                               \
    }                                                                                   \
} while (0)

// ---------------- KA: fused flash attention + output projection ----------------
// R13 math path (bias as f32 C operand, f32 exp2, pk4, f32 l) + V double-buffer.
__global__ __launch_bounds__(512) __attribute__((amdgpu_waves_per_eu(2, 8)))
void ka_fused(const h16* __restrict__ qkv,
              const h16* __restrict__ Bi,
              const h16* __restrict__ wToT,
              const float* __restrict__ bout,
              float* __restrict__ out,
              unsigned long wstr, unsigned long ostr)
{
    __shared__ __align__(16) h16 as[64 * 264];     // attn result [tok][ch], pad 264
    const int b = blockIdx.y;
    const h16* qb = qkv + (unsigned long)b * wstr;
    float* outb = out + (unsigned long)b * ostr;

    const int tid = threadIdx.x;
    const int lane = tid & 63, hh = tid >> 6;
    const int c = lane & 15, hi = lane >> 4;
    const int bid = blockIdx.x;                    // XCD swizzle: 512 blocks, 8 XCDs
    const int blk = (bid & 7) * 64 + (bid >> 3);   // window-contiguous per XCD
    const int sq = blk & 7, w = blk >> 3;
    const int qbase = sq * 64;
    const int base = w * 8 + hh;
    const h16* Qp = qb + base * (512 * 32);
    const h16* Kp = qb + KOFF_H + base * (512 * 32);
    const h16* Vp = qb + VOFF_H + base * VT_WH;
    const h16* Bq = Bi + sq * 32768 + (hi * 16 + c) * 8;   // fragment-ordered bias (log2 domain)

    h8_t qf[4];
#pragma unroll
    for (int cf = 0; cf < 4; ++cf)
        qf[cf] = *(const h8_t*)(Qp + (qbase + cf * 16 + c) * 32 + hi * 8);

    f4_t acc[4][2];                                // [cf][dh]: rows q=hi*4+reg, cols d=c
#pragma unroll
    for (int i = 0; i < 4; ++i)
#pragma unroll
        for (int j = 0; j < 2; ++j) { f4_t z = {0.f, 0.f, 0.f, 0.f}; acc[i][j] = z; }
    float l[4] = {0.f, 0.f, 0.f, 0.f};

    h8_t kfA[2], kfB[2];                           // named dbuf K frags
    h8_t bbA[4], bbB[4];                           // named dbuf bias frags [rf*2+cfp]
    h8_t vvA[2], vvB[2];                           // named dbuf V frags [dh]

    // prologue: chunk 0 into A
    kfA[0] = *(const h8_t*)(Kp + c * 32 + hi * 8);
    kfA[1] = *(const h8_t*)(Kp + (16 + c) * 32 + hi * 8);
    vvA[0] = *(const h8_t*)(Vp + lane * 8);
    vvA[1] = *(const h8_t*)(Vp + 512 + lane * 8);
#pragma unroll
    for (int t = 0; t < 4; ++t)
        bbA[t] = *(const h8_t*)(Bq + t * 512);

#pragma unroll 1
    for (int kc2 = 0; kc2 < 8; ++kc2) {
        KA_PHASE(kfA, bbA, vvA, kfB, bbB, vvB, kc2 * 2, 1);
        KA_PHASE(kfB, bbB, vvB, kfA, bbA, vvA, kc2 * 2 + 1, kc2 < 7);
    }

    // l cross-reduce (per q = cf*16+c)
#pragma unroll
    for (int cf = 0; cf < 4; ++cf) {
        l[cf] += __shfl_xor(l[cf], 16);
        l[cf] += __shfl_xor(l[cf], 32);
    }

    // normalize (l at q = hi*4+reg via shfl) and stage in LDS
#pragma unroll
    for (int cf = 0; cf < 4; ++cf) {
#pragma unroll
        for (int r = 0; r < 4; ++r) {
            float rl = __builtin_amdgcn_rcpf(__shfl(l[cf], hi * 4 + r));
            const int tok = cf * 16 + hi * 4 + r;
#pragma unroll
            for (int dh = 0; dh < 2; ++dh)
                as[tok * 264 + hh * 32 + dh * 16 + c] = (h16)(acc[cf][dh][r] * rl);
        }
    }
    __syncthreads();

    // ---- output projection: wave hh -> output channels [hh*32, hh*32+32) ----
    f4_t pacc[2][4];
#pragma unroll
    for (int i = 0; i < 2; ++i)
#pragma unroll
        for (int j = 0; j < 4; ++j) { f4_t z = {0.f, 0.f, 0.f, 0.f}; pacc[i][j] = z; }

#pragma unroll 2
    for (int ks = 0; ks < 8; ++ks) {
        h8_t a2[2], b2[4];
#pragma unroll
        for (int rf = 0; rf < 2; ++rf)
            a2[rf] = *(const h8_t*)(wToT + (hh * 32 + rf * 16 + c) * 256 + ks * 32 + hi * 8);
#pragma unroll
        for (int cf = 0; cf < 4; ++cf)
            b2[cf] = *(const h8_t*)(as + (cf * 16 + c) * 264 + ks * 32 + hi * 8);
#pragma unroll
        for (int rf = 0; rf < 2; ++rf)
#pragma unroll
            for (int cf = 0; cf < 4; ++cf)
                pacc[rf][cf] = __builtin_amdgcn_mfma_f32_16x16x32_f16(a2[rf], b2[cf], pacc[rf][cf], 0, 0, 0);
    }

    const int wh = w >> 4, ww = (w >> 2) & 3, wd = w & 3;
    const int X = (wh * 8 + sq + 4) & 31;
#pragma unroll
    for (int cf = 0; cf < 4; ++cf) {
        const int tl = cf * 16 + c;
        const int Y = (ww * 8 + (tl >> 3) + 4) & 31;
        const int Z = (wd * 8 + (tl & 7) + 4) & 31;
        float* op = outb + ((X * 32 + Y) * 32 + Z) * 256;
#pragma unroll
        for (int rf = 0; rf < 2; ++rf) {
            const int co = hh * 32 + rf * 16 + hi * 4;
            f4_t bo = *(const f4_t*)(bout + co);
            f4_t v = pacc[rf][cf];
            v[0] += bo[0]; v[1] += bo[1]; v[2] += bo[2]; v[3] += bo[3];
            *(f4_t*)(op + co) = v;
        }
    }
}

extern "C" void kernel_launch(void* const* d_in, const int* in_sizes, int n_in,
                              void* d_out, int out_size, void* d_ws, size_t ws_size,
                              hipStream_t stream)
{
    (void)in_sizes; (void)n_in; (void)out_size;
    const float* x    = (const float*)d_in[0];
    const float* wqkv = (const float*)d_in[1];
    const float* pos  = (const float*)d_in[2];
    const float* wout = (const float*)d_in[3];
    const float* bout = (const float*)d_in[4];
    float* out = (float*)d_out;
    char* ws = (char*)d_ws;

    h16* bias = (h16*)(ws + OFF_BIAS);
    h16* wT   = (h16*)(ws + OFF_WQKV);
    h16* wToT = (h16*)(ws + OFF_WOUT);
    h16* qkv  = (h16*)(ws + OFF_QKV);

    const unsigned long BSTR = 32768ul * 256ul;   // per-batch elements of x / out

    k0_prep<<<2048, 256, 0, stream>>>(wqkv, pos, wout, bias, wT, wToT);

    if (ws_size >= (size_t)OFF_QKV + 2ul * WS_BBYTES) {
        k1_qkv<<<dim3(512, 2), 768, 0, stream>>>(x, wT, qkv, BSTR, WSTR_H);
        ka_fused<<<dim3(512, 2), 512, 0, stream>>>(qkv, bias, wToT, bout, out, WSTR_H, BSTR);
    } else {
        for (int b = 0; b < 2; ++b) {
            k1_qkv<<<dim3(512, 1), 768, 0, stream>>>(x + b * BSTR, wT, qkv, 0, 0);
            ka_fused<<<dim3(512, 1), 512, 0, stream>>>(qkv, bias, wToT, bout, out + b * BSTR, 0, 0);
        }
    }
}

// Round 18
// 171.141 us; speedup vs baseline: 1.0114x; 1.0114x over previous
//
#include <hip/hip_runtime.h>

typedef _Float16 h16;
typedef h16 h8_t __attribute__((ext_vector_type(8)));
typedef h16 h4_t __attribute__((ext_vector_type(4)));
typedef float f4_t __attribute__((ext_vector_type(4)));
typedef unsigned int u32;
typedef u32 u4_t __attribute__((ext_vector_type(4)));

#define LOG2E 1.4426950408889634f
// (1/sqrt(32)) * log2(e)  -- folded into q columns of w_qkv^T
#define QSCALE 0.25505998f
#define SOFF 4.0f              // fixed softmax offset, folded into the bias table (log2 domain)

// workspace byte offsets
#define OFF_BIAS 0u
#define OFF_WQKV 524288u
#define OFF_WOUT 917504u
#define OFF_QKV  1048576u
// per-batch qkv block: Q 16MiB | K 16MiB | VT(B-frag order) 16MiB = 48MiB
#define WS_BBYTES 50331648u
#define WSTR_H    25165824u     // h16 elements per batch block
#define KOFF_H    8388608u      // K offset within block (h16 elems)
#define VOFF_H    16777216u     // VT offset within block
#define VT_WH     16384u        // h16 per (w,h) in VT

static __device__ __forceinline__ u32 pkrtz(float a, float b) {
    return __builtin_bit_cast(u32, __builtin_amdgcn_cvt_pkrtz(a, b));
}
static __device__ __forceinline__ h4_t pk4(float a, float b, float c, float d) {
    uint2 t; t.x = pkrtz(a, b); t.y = pkrtz(c, d);
    return __builtin_bit_cast(h4_t, t);
}

// ---------------- K0: precompute bias (fragment-ordered, log2 domain, -SOFF), w_qkv^T, w_out^T ----------------
// bias layout: [sq][kc][rf][cfp][hi*16+c][cf2][e]  (one b128 per (sq,kc,rf,cfp) per lane)
__global__ __launch_bounds__(256) void k0_prep(const float* __restrict__ wqkv,
                                               const float* __restrict__ pos,
                                               const float* __restrict__ wout,
                                               h16* __restrict__ bias,
                                               h16* __restrict__ wT,
                                               h16* __restrict__ wToT)
{
    const int bid = blockIdx.x;
    const int e = bid * 256 + threadIdx.x;
    if (bid < 1024) {
        int o = e;                      // 0..262143
        int e4  = o & 3;
        int cf2 = (o >> 2) & 1;
        int c   = (o >> 3) & 15;
        int hi  = (o >> 7) & 3;
        int cfp = (o >> 9) & 1;
        int rf  = (o >> 10) & 1;
        int kc  = (o >> 11) & 15;
        int sq  = o >> 15;
        int i = sq * 64 + (cfp * 2 + cf2) * 16 + c;   // query token
        int j = kc * 32 + rf * 16 + hi * 4 + e4;      // key token
        int ix = i >> 6, iy = (i >> 3) & 7, iz = i & 7;
        int jx = j >> 6, jy = (j >> 3) & 7, jz = j & 7;
        int r0 = jx - ix + 7, r1 = jy - iy + 7, r2 = jz - iz + 7;
        float v = pos[(r0 * 15 + r1) * 15 + r2] * LOG2E - SOFF;
        bias[o] = (h16)v;
    } else if (bid < 1792) {
        int t = e - 1024 * 256;
        int n = t >> 8, k = t & 255;
        float v = wqkv[k * 768 + n];
        if (n < 256) v *= QSCALE;          // scale the q channels
        wT[n * 256 + k] = (h16)v;
    } else {
        int t = e - 1792 * 256;
        int n = t >> 8, k = t & 255;
        wToT[n * 256 + k] = (h16)wout[k * 256 + n];
    }
}

// ---------------- K1: QKV projection, fused roll + window reorder ----------------
// V stored in exact MFMA-B-frag order: VT[(w,h)][kc][dh][lane=hi*16+c][rf*4+e]
// V epilogue goes through LDS (xs reuse) so global V stores are coalesced b128
// (R12 lesson: 64 scalar 2B stores per V-wave made k1 store-pipe-bound, 66->107us).
__global__ __launch_bounds__(768) __attribute__((amdgpu_waves_per_eu(3, 6)))
void k1_qkv(const float* __restrict__ x,
            const h16* __restrict__ wT,
            h16* __restrict__ qkv,
            unsigned long xstr, unsigned long wstr)
{
    __shared__ __align__(16) h16 xs[64 * 256];   // 32KB: fp16 x-tile, then V staging
    const int b = blockIdx.y;
    const float* xb = x + (unsigned long)b * xstr;
    h16* Qo = qkv + (unsigned long)b * wstr;
    h16* Ko = Qo + KOFF_H;
    h16* Vt = Qo + VOFF_H;

    const int tid = threadIdx.x;
    const int tile = blockIdx.x;                  // w*8 + st
    const int st = tile & 7, w = tile >> 3;
    const int wh = w >> 4, ww = (w >> 2) & 3, wd = w & 3;
    const int Xs = (wh * 8 + st + 4) & 31;        // roll(-4)

    for (int i = tid; i < 4096; i += 768) {       // 64 rows x 64 16B-segments (f32)
        int row = i >> 6, seg = i & 63;
        int iw = row >> 3, id = row & 7;
        int Y = (ww * 8 + iw + 4) & 31, Z = (wd * 8 + id + 4) & 31;
        const float* xp = xb + ((Xs * 32 + Y) * 32 + Z) * 256 + seg * 4;
        f4_t v = *(const f4_t*)xp;
        uint2 tmp;
        tmp.x = pkrtz(v[0], v[1]);
        tmp.y = pkrtz(v[2], v[3]);
        *(uint2*)((char*)xs + row * 512 + (((u32)(seg * 8)) ^ ((u32)(row & 7) << 4))) = tmp;
    }
    __syncthreads();

    const int wv = tid >> 6, lane = tid & 63;
    const int c = lane & 15, hi = lane >> 4;
    f4_t acc[4][4];
#pragma unroll
    for (int i = 0; i < 4; ++i)
#pragma unroll
        for (int j = 0; j < 4; ++j) { f4_t z = {0.f, 0.f, 0.f, 0.f}; acc[i][j] = z; }

#pragma unroll 2
    for (int ks = 0; ks < 8; ++ks) {
        h8_t a[4], bfr[4];
#pragma unroll
        for (int rf = 0; rf < 4; ++rf)
            a[rf] = *(const h8_t*)(wT + (wv * 64 + rf * 16 + c) * 256 + ks * 32 + hi * 8);
#pragma unroll
        for (int cf = 0; cf < 4; ++cf) {
            int tok = cf * 16 + c;
            bfr[cf] = *(const h8_t*)((const char*)xs + tok * 512 +
                                     (((u32)(ks * 64 + hi * 16)) ^ ((u32)(tok & 7) << 4)));
        }
#pragma unroll
        for (int rf = 0; rf < 4; ++rf)
#pragma unroll
            for (int cf = 0; cf < 4; ++cf)
                acc[rf][cf] = __builtin_amdgcn_mfma_f32_16x16x32_f16(a[rf], bfr[cf], acc[rf][cf], 0, 0, 0);
    }

    const int wbh = w * 8;
    // Q/K waves: direct global stores (8B, line-assembling across rf) -- no xs dependency
    if (wv < 8) {
#pragma unroll
        for (int rf = 0; rf < 4; ++rf) {
            const int ch = wv * 64 + rf * 16 + hi * 4;
            const int sel = ch >> 8;                  // 0=q 1=k (uniform per wave)
            const int ch2 = ch & 255, hh2 = ch2 >> 5, d0 = ch2 & 31;
#pragma unroll
            for (int cf = 0; cf < 4; ++cf) {
                const int t = st * 64 + cf * 16 + c;
                f4_t v = acc[rf][cf];
                h16* qp = (sel ? Ko : Qo) + ((wbh + hh2) * 512 + t) * 32 + d0;
                uint2 sv;
                sv.x = pkrtz(v[0], v[1]);
                sv.y = pkrtz(v[2], v[3]);
                *(uint2*)qp = sv;
            }
        }
    }
    __syncthreads();          // all xs READS (bfr) complete before V staging overwrites
    if (wv >= 8) {
        // V waves: scatter h16 into xs at B-frag offsets (identical algebra to the
        // R11/R12-proven direct store; st*64 multiples drop out of the low bits)
#pragma unroll
        for (int rf = 0; rf < 4; ++rf) {
            const int ch2 = (wv - 8) * 64 + rf * 16 + hi * 4;
            const int hh2 = ch2 >> 5, d0 = ch2 & 31;
            const int bh = hh2 * 2048 + (d0 >> 4) * 512 + (d0 & 15) * 8;
#pragma unroll
            for (int cf = 0; cf < 4; ++cf) {
                const int tl = cf * 16 + c;
                const int bt = (tl >> 5) * 1024 + ((tl >> 2) & 3) * 128 +
                               ((tl >> 4) & 1) * 4 + (tl & 3);
                f4_t v = acc[rf][cf];
#pragma unroll
                for (int r = 0; r < 4; ++r)
                    xs[bh + bt + r * 8] = (h16)v[r];
            }
        }
    }
    __syncthreads();          // V staging complete
    // cooperative coalesced copy: 2048 x 16B chunks; per head one contiguous 4KB run
    {
        h16* Vw = Vt + (unsigned long)wbh * VT_WH + st * 2048;
        for (int i = tid; i < 2048; i += 768) {
            const int hh2 = i >> 8, rem = i & 255;
            h8_t vchunk = *(const h8_t*)(xs + i * 8);
            *(h8_t*)(Vw + hh2 * VT_WH + rem * 8) = vchunk;
        }
    }
}

// One kv-chunk phase, ILP-SPLIT (R18): (A) all 8 QK MFMAs back-to-back into s[][],
// (B) all exp2/pack VALU (inputs long ready -> no MFMA-latency stalls),
// (C) all 16 PV MFMAs back-to-back. All arrays compile-time-indexed (rule #20 safe).
#define KA_PHASE(KFC, BBC, VVC, KFN, BBN, VVN, KC, PREF) do {                           \
    if (PREF) {                                                                         \
        const int kt1_ = ((KC) + 1) * 32;                                               \
        KFN[0] = *(const h8_t*)(Kp + (kt1_ + c) * 32 + hi * 8);                         \
        KFN[1] = *(const h8_t*)(Kp + (kt1_ + 16 + c) * 32 + hi * 8);                    \
        VVN[0] = *(const h8_t*)(Vp + ((KC) + 1) * 1024 + lane * 8);                     \
        VVN[1] = *(const h8_t*)(Vp + ((KC) + 1) * 1024 + 512 + lane * 8);               \
        _Pragma("unroll")                                                               \
        for (int t = 0; t < 4; ++t)                                                     \
            BBN[t] = *(const h8_t*)(Bq + (((KC) + 1) * 4 + t) * 512);                   \
    }                                                                                   \
    f4_t s[2][4];                                                                       \
    _Pragma("unroll")                                                                   \
    for (int rf = 0; rf < 2; ++rf)                                                      \
        _Pragma("unroll")                                                               \
        for (int cfp = 0; cfp < 2; ++cfp) {                                             \
            h8_t bv = BBC[rf * 2 + cfp];                                                \
            _Pragma("unroll")                                                           \
            for (int cf2 = 0; cf2 < 2; ++cf2) {                                         \
                const int cf = cfp * 2 + cf2;                                           \
                f4_t si;                                                                \
                si[0] = (float)bv[cf2 * 4 + 0];                                         \
                si[1] = (float)bv[cf2 * 4 + 1];                                         \
                si[2] = (float)bv[cf2 * 4 + 2];                                         \
                si[3] = (float)bv[cf2 * 4 + 3];                                         \
                s[rf][cf] = __builtin_amdgcn_mfma_f32_16x16x32_f16(KFC[rf], qf[cf], si, 0, 0, 0); \
            }                                                                           \
        }                                                                               \
    h4_t pa[2][4];                                                                      \
    _Pragma("unroll")                                                                   \
    for (int rf = 0; rf < 2; ++rf)                                                      \
        _Pragma("unroll")                                                               \
        for (int cf = 0; cf < 4; ++cf) {                                                \
            float p0 = __builtin_amdgcn_exp2f(s[rf][cf][0]);                            \
            float p1 = __builtin_amdgcn_exp2f(s[rf][cf][1]);                            \
            float p2 = __builtin_amdgcn_exp2f(s[rf][cf][2]);                            \
            float p3 = __builtin_amdgcn_exp2f(s[rf][cf][3]);                            \
            l[cf] += (p0 + p1) + (p2 + p3);                                             \
            pa[rf][cf] = pk4(p0, p1, p2, p3);                                           \
        }                                                                               \
    const u4_t vw0 = __builtin_bit_cast(u4_t, VVC[0]);                                  \
    const u4_t vw1 = __builtin_bit_cast(u4_t, VVC[1]);                                  \
    _Pragma("unroll")                                                                   \
    for (int rf = 0; rf < 2; ++rf) {                                                    \
        uint2 vt0; vt0.x = vw0[rf * 2]; vt0.y = vw0[rf * 2 + 1];                        \
        uint2 vt1; vt1.x = vw1[rf * 2]; vt1.y = vw1[rf * 2 + 1];                        \
        const h4_t vB0 = __builtin_bit_cast(h4_t, vt0);                                 \
        const h4_t vB1 = __builtin_bit_cast(h4_t, vt1);                                 \
        _Pragma("unroll")                                                               \
        for (int cf = 0; cf < 4; ++cf) {                                                \
            acc[cf][0] = __builtin_amdgcn_mfma_f32_16x16x16f16(pa[rf][cf], vB0, acc[cf][0], 0, 0, 0); \
            acc[cf][1] = __builtin_amdgcn_mfma_f32_16x16x16f16(pa[rf][cf], vB1, acc[cf][1], 0, 0, 0); \
        }                                                                               \
    }                                                                                   \
} while (0)

// ---------------- KA: fused flash attention + output projection ----------------
// R13 math path (bias as f32 C operand, f32 exp2, pk4, f32 l) + V dbuf + ILP split.
__global__ __launch_bounds__(512) __attribute__((amdgpu_waves_per_eu(2, 8)))
void ka_fused(const h16* __restrict__ qkv,
              const h16* __restrict__ Bi,
              const h16* __restrict__ wToT,
              const float* __restrict__ bout,
              float* __restrict__ out,
              unsigned long wstr, unsigned long ostr)
{
    __shared__ __align__(16) h16 as[64 * 264];     // attn result [tok][ch], pad 264
    const int b = blockIdx.y;
    const h16* qb = qkv + (unsigned long)b * wstr;
    float* outb = out + (unsigned long)b * ostr;

    const int tid = threadIdx.x;
    const int lane = tid & 63, hh = tid >> 6;
    const int c = lane & 15, hi = lane >> 4;
    const int bid = blockIdx.x;                    // XCD swizzle: 512 blocks, 8 XCDs
    const int blk = (bid & 7) * 64 + (bid >> 3);   // window-contiguous per XCD
    const int sq = blk & 7, w = blk >> 3;
    const int qbase = sq * 64;
    const int base = w * 8 + hh;
    const h16* Qp = qb + base * (512 * 32);
    const h16* Kp = qb + KOFF_H + base * (512 * 32);
    const h16* Vp = qb + VOFF_H + base * VT_WH;
    const h16* Bq = Bi + sq * 32768 + (hi * 16 + c) * 8;   // fragment-ordered bias (log2 domain)

    h8_t qf[4];
#pragma unroll
    for (int cf = 0; cf < 4; ++cf)
        qf[cf] = *(const h8_t*)(Qp + (qbase + cf * 16 + c) * 32 + hi * 8);

    f4_t acc[4][2];                                // [cf][dh]: rows q=hi*4+reg, cols d=c
#pragma unroll
    for (int i = 0; i < 4; ++i)
#pragma unroll
        for (int j = 0; j < 2; ++j) { f4_t z = {0.f, 0.f, 0.f, 0.f}; acc[i][j] = z; }
    float l[4] = {0.f, 0.f, 0.f, 0.f};

    h8_t kfA[2], kfB[2];                           // named dbuf K frags
    h8_t bbA[4], bbB[4];                           // named dbuf bias frags [rf*2+cfp]
    h8_t vvA[2], vvB[2];                           // named dbuf V frags [dh]

    // prologue: chunk 0 into A
    kfA[0] = *(const h8_t*)(Kp + c * 32 + hi * 8);
    kfA[1] = *(const h8_t*)(Kp + (16 + c) * 32 + hi * 8);
    vvA[0] = *(const h8_t*)(Vp + lane * 8);
    vvA[1] = *(const h8_t*)(Vp + 512 + lane * 8);
#pragma unroll
    for (int t = 0; t < 4; ++t)
        bbA[t] = *(const h8_t*)(Bq + t * 512);

#pragma unroll 1
    for (int kc2 = 0; kc2 < 8; ++kc2) {
        KA_PHASE(kfA, bbA, vvA, kfB, bbB, vvB, kc2 * 2, 1);
        KA_PHASE(kfB, bbB, vvB, kfA, bbA, vvA, kc2 * 2 + 1, kc2 < 7);
    }

    // l cross-reduce (per q = cf*16+c)
#pragma unroll
    for (int cf = 0; cf < 4; ++cf) {
        l[cf] += __shfl_xor(l[cf], 16);
        l[cf] += __shfl_xor(l[cf], 32);
    }

    // normalize (l at q = hi*4+reg via shfl) and stage in LDS
#pragma unroll
    for (int cf = 0; cf < 4; ++cf) {
#pragma unroll
        for (int r = 0; r < 4; ++r) {
            float rl = __builtin_amdgcn_rcpf(__shfl(l[cf], hi * 4 + r));
            const int tok = cf * 16 + hi * 4 + r;
#pragma unroll
            for (int dh = 0; dh < 2; ++dh)
                as[tok * 264 + hh * 32 + dh * 16 + c] = (h16)(acc[cf][dh][r] * rl);
        }
    }
    __syncthreads();

    // ---- output projection: wave hh -> output channels [hh*32, hh*32+32) ----
    f4_t pacc[2][4];
#pragma unroll
    for (int i = 0; i < 2; ++i)
#pragma unroll
        for (int j = 0; j < 4; ++j) { f4_t z = {0.f, 0.f, 0.f, 0.f}; pacc[i][j] = z; }

#pragma unroll 2
    for (int ks = 0; ks < 8; ++ks) {
        h8_t a2[2], b2[4];
#pragma unroll
        for (int rf = 0; rf < 2; ++rf)
            a2[rf] = *(const h8_t*)(wToT + (hh * 32 + rf * 16 + c) * 256 + ks * 32 + hi * 8);
#pragma unroll
        for (int cf = 0; cf < 4; ++cf)
            b2[cf] = *(const h8_t*)(as + (cf * 16 + c) * 264 + ks * 32 + hi * 8);
#pragma unroll
        for (int rf = 0; rf < 2; ++rf)
#pragma unroll
            for (int cf = 0; cf < 4; ++cf)
                pacc[rf][cf] = __builtin_amdgcn_mfma_f32_16x16x32_f16(a2[rf], b2[cf], pacc[rf][cf], 0, 0, 0);
    }

    const int wh = w >> 4, ww = (w >> 2) & 3, wd = w & 3;
    const int X = (wh * 8 + sq + 4) & 31;
#pragma unroll
    for (int cf = 0; cf < 4; ++cf) {
        const int tl = cf * 16 + c;
        const int Y = (ww * 8 + (tl >> 3) + 4) & 31;
        const int Z = (wd * 8 + (tl & 7) + 4) & 31;
        float* op = outb + ((X * 32 + Y) * 32 + Z) * 256;
#pragma unroll
        for (int rf = 0; rf < 2; ++rf) {
            const int co = hh * 32 + rf * 16 + hi * 4;
            f4_t bo = *(const f4_t*)(bout + co);
            f4_t v = pacc[rf][cf];
            v[0] += bo[0]; v[1] += bo[1]; v[2] += bo[2]; v[3] += bo[3];
            *(f4_t*)(op + co) = v;
        }
    }
}

extern "C" void kernel_launch(void* const* d_in, const int* in_sizes, int n_in,
                              void* d_out, int out_size, void* d_ws, size_t ws_size,
                              hipStream_t stream)
{
    (void)in_sizes; (void)n_in; (void)out_size;
    const float* x    = (const float*)d_in[0];
    const float* wqkv = (const float*)d_in[1];
    const float* pos  = (const float*)d_in[2];
    const float* wout = (const float*)d_in[3];
    const float* bout = (const float*)d_in[4];
    float* out = (float*)d_out;
    char* ws = (char*)d_ws;

    h16* bias = (h16*)(ws + OFF_BIAS);
    h16* wT   = (h16*)(ws + OFF_WQKV);
    h16* wToT = (h16*)(ws + OFF_WOUT);
    h16* qkv  = (h16*)(ws + OFF_QKV);

    const unsigned long BSTR = 32768ul * 256ul;   // per-batch elements of x / out

    k0_prep<<<2048, 256, 0, stream>>>(wqkv, pos, wout, bias, wT, wToT);

    if (ws_size >= (size_t)OFF_QKV + 2ul * WS_BBYTES) {
        k1_qkv<<<dim3(512, 2), 768, 0, stream>>>(x, wT, qkv, BSTR, WSTR_H);
        ka_fused<<<dim3(512, 2), 512, 0, stream>>>(qkv, bias, wToT, bout, out, WSTR_H, BSTR);
    } else {
        for (int b = 0; b < 2; ++b) {
            k1_qkv<<<dim3(512, 1), 768, 0, stream>>>(x + b * BSTR, wT, qkv, 0, 0);
            ka_fused<<<dim3(512, 1), 512, 0, stream>>>(qkv, bias, wToT, bout, out + b * BSTR, 0, 0);
        }
    }
}